// Round 18
// baseline (483.128 us; speedup 1.0000x reference)
//
#include <hip/hip_runtime.h>
#include <hip/hip_bf16.h>
#include <math.h>

#define B_   4
#define H_   8
#define NQ_  2048
#define NK_  2048
#define DM_  512
#define DK_  64
#define WL_  262144   // 512*512

typedef short  bf16x8 __attribute__((ext_vector_type(8)));
typedef float  f32x4  __attribute__((ext_vector_type(4)));

static __device__ __forceinline__ f32x4 MFMA16(bf16x8 a, bf16x8 b, f32x4 c) {
    return __builtin_amdgcn_mfma_f32_16x16x32_bf16(a, b, c, 0, 0, 0);
}
static __device__ __forceinline__ unsigned short f2bf(float f) {
    __hip_bfloat16 h = __float2bfloat16(f);
    unsigned short u; __builtin_memcpy(&u, &h, 2); return u;
}
static __device__ __forceinline__ float bf2f(unsigned short u) {
    unsigned int x = ((unsigned int)u) << 16;
    float f; __builtin_memcpy(&f, &x, 4); return f;
}
static __device__ __forceinline__ void glds16(const void* g, void* l) {
    __builtin_amdgcn_global_load_lds(
        (__attribute__((address_space(1))) const void*)g,
        (__attribute__((address_space(3))) void*)l, 16, 0, 0);
}

// ---------------------------------------------------------------------------
// W (512x512 fp32, [k][n]) -> WT_hi/WT_lo (bf16, [n][k]) for all 4 weights
// ---------------------------------------------------------------------------
__global__ __launch_bounds__(256) void wprep(const float* __restrict__ Wq,
                                             const float* __restrict__ Wk,
                                             const float* __restrict__ Wv,
                                             const float* __restrict__ Wo,
                                             unsigned short* __restrict__ out)
{
    __shared__ float tile[64][65];
    const int tid = threadIdx.x;
    const int k0 = blockIdx.x * 64, n0 = blockIdx.y * 64, w = blockIdx.z;
    const float* W = (w == 0) ? Wq : (w == 1) ? Wk : (w == 2) ? Wv : Wo;
    unsigned short* WTh = out + (size_t)w * 2 * WL_;
    unsigned short* WTl = WTh + WL_;

#pragma unroll
    for (int rd = 0; rd < 4; ++rd) {
        const int k = (tid >> 4) + 16*rd, c4 = (tid & 15) * 4;
        const float4 v4 = *(const float4*)(W + (size_t)(k0 + k)*DM_ + n0 + c4);
        tile[k][c4+0] = v4.x; tile[k][c4+1] = v4.y;
        tile[k][c4+2] = v4.z; tile[k][c4+3] = v4.w;
    }
    __syncthreads();
#pragma unroll
    for (int rd = 0; rd < 4; ++rd) {
        const int n = (tid >> 4) + 16*rd, kk = (tid & 15) * 4;
        unsigned short hh[4], ll[4];
#pragma unroll
        for (int j = 0; j < 4; ++j) {
            const float f = tile[kk + j][n];
            hh[j] = f2bf(f);
            ll[j] = f2bf(f - bf2f(hh[j]));
        }
        *(ushort4*)(WTh + (size_t)(n0 + n)*DM_ + k0 + kk) = make_ushort4(hh[0],hh[1],hh[2],hh[3]);
        *(ushort4*)(WTl + (size_t)(n0 + n)*DM_ + k0 + kk) = make_ushort4(ll[0],ll[1],ll[2],ll[3]);
    }
}

// ---------------------------------------------------------------------------
// FUSED: 3 projection GEMMs (z=0,1,2) + mask->bits conversion (z=3,4).
// ---------------------------------------------------------------------------
__global__ __launch_bounds__(256) void proj_mask(
    const float* __restrict__ q, const float* __restrict__ k,
    const float* __restrict__ v,
    const unsigned short* __restrict__ wt,
    const float* __restrict__ bq, const float* __restrict__ bk,
    const float* __restrict__ bv,
    unsigned short* __restrict__ q_bf, unsigned short* __restrict__ k_bf,
    unsigned short* __restrict__ vT,
    const unsigned char* __restrict__ Mk,
    unsigned long long* __restrict__ bits)
{
    __shared__ unsigned short Ah[64][64], Bh[64][64], Bl[64][64];
    __shared__ int s_flag;

    const int tid = threadIdx.x;
    const int z = blockIdx.z;

    if (z < 3) {
        const float* A = (z == 0) ? q : (z == 1) ? k : v;
        const unsigned short* WTh = wt + (size_t)(2*z) * WL_;
        const unsigned short* WTl = WTh + WL_;
        const float* bias = (z == 0) ? bq : (z == 1) ? bk : bv;
        const float oscale = (z == 0) ? 0.125f : 1.0f;
        const int mode = (z == 2) ? 1 : 0;

        const int w = tid >> 6, lane = tid & 63, g = lane >> 4, r = lane & 15;
        const int m0 = blockIdx.x * 64, n0 = blockIdx.y * 64;

        char* pAh = (char*)&Ah[0][0];
        char* pBh = (char*)&Bh[0][0];
        char* pBl = (char*)&Bl[0][0];

        const f32x4 z4 = {0.f, 0.f, 0.f, 0.f};
        f32x4 acc[4] = {z4, z4, z4, z4};

        for (int kt = 0; kt < DM_; kt += 64) {
#pragma unroll
            for (int rd = 0; rd < 4; ++rd) {
                const int row = (tid >> 4) + 16*rd;
                const int c4  = (tid & 15) * 4;
                const float4 a4 = *(const float4*)(A + (size_t)(m0 + row)*DM_ + kt + c4);
                const float av[4] = {a4.x, a4.y, a4.z, a4.w};
                unsigned short hh[4];
#pragma unroll
                for (int j = 0; j < 4; ++j) hh[j] = f2bf(av[j]);
                const int bo = (c4 * 2) ^ ((row & 7) << 4);
                *(ushort4*)(pAh + row*128 + bo) = make_ushort4(hh[0],hh[1],hh[2],hh[3]);
            }
#pragma unroll
            for (int rd = 0; rd < 2; ++rd) {
                const int idx = tid + 256*rd;
                const int row = idx >> 3;
                const int cb  = (idx & 7) * 16;
                const int bo  = cb ^ ((row & 7) << 4);
                const size_t goff = (size_t)(n0 + row)*DM_ + kt + (cb >> 1);
                *(bf16x8*)(pBh + row*128 + bo) = *(const bf16x8*)(WTh + goff);
                *(bf16x8*)(pBl + row*128 + bo) = *(const bf16x8*)(WTl + goff);
            }
            __syncthreads();

            const int swr = (r & 7) << 4;
#pragma unroll
            for (int ks = 0; ks < 2; ++ks) {
                const int xo = (64*ks + 16*g) ^ swr;
                const bf16x8 xh = *(const bf16x8*)(pAh + (16*w + r)*128 + xo);
#pragma unroll
                for (int nt = 0; nt < 4; ++nt) {
                    const bf16x8 bh = *(const bf16x8*)(pBh + (16*nt + r)*128 + xo);
                    const bf16x8 bl = *(const bf16x8*)(pBl + (16*nt + r)*128 + xo);
                    if (mode == 1) {
                        acc[nt] = MFMA16(xh, bh, acc[nt]);
                        acc[nt] = MFMA16(xh, bl, acc[nt]);
                    } else {
                        acc[nt] = MFMA16(bh, xh, acc[nt]);
                        acc[nt] = MFMA16(bl, xh, acc[nt]);
                    }
                }
            }
            __syncthreads();
        }

        if (mode == 0) {
            const int m = m0 + 16*w + r;
            const int b = m >> 11, qq = m & 2047, h = blockIdx.y;
            unsigned short* dstp = (z == 0 ? q_bf : k_bf) +
                                   (((size_t)(b*H_ + h))*NQ_ + qq)*DK_;
#pragma unroll
            for (int nt = 0; nt < 4; ++nt) {
                unsigned short u[4];
#pragma unroll
                for (int j = 0; j < 4; ++j)
                    u[j] = f2bf((acc[nt][j] + bias[n0 + 16*nt + 4*g + j]) * oscale);
                *(ushort4*)(dstp + 16*nt + 4*g) = make_ushort4(u[0],u[1],u[2],u[3]);
            }
        } else {
            const int b = m0 >> 11, h = blockIdx.y;
            const int key = (m0 & 2047) + 16*w + 4*g;
#pragma unroll
            for (int nt = 0; nt < 4; ++nt) {
                const int dv = 16*nt + r;
                const float bvv = bias[n0 + dv];
                unsigned short u[4];
#pragma unroll
                for (int j = 0; j < 4; ++j) u[j] = f2bf(acc[nt][j] + bvv);
                *(ushort4*)(vT + (((size_t)(b*H_ + h))*DK_ + dv)*NK_ + key) =
                    make_ushort4(u[0],u[1],u[2],u[3]);
            }
        }
    } else {
        // ---------------- mask -> bits (grid-stride) ----------------
        if (tid == 0) s_flag = 0;
        __syncthreads();
        {
            bool any = false;
#pragma unroll
            for (int i = 1; i < 16; i += 4)
                if (Mk[tid*16 + i]) any = true;
            if (any) s_flag = 1;
        }
        __syncthreads();

        const long long NELEM = (long long)B_*H_*NQ_*NK_;      // 128Mi
        const long long nblk  = 2LL * gridDim.x * gridDim.y;   // 2048
        const long long nth   = nblk * 256;
        const long long id    = ((long long)(z - 3) * gridDim.x * gridDim.y +
                                 (long long)blockIdx.y * gridDim.x + blockIdx.x);
        const long long T     = id * 256 + tid;
        unsigned short* b16   = (unsigned short*)bits;
        const uint4*    src   = (const uint4*)Mk;

        if (s_flag) {
            const long long n = NELEM / 16;
            for (long long t = T; t < n; t += nth) {
                const uint4 u = src[t];
                const unsigned int w[4] = {u.x, u.y, u.z, u.w};
                unsigned int m = 0;
#pragma unroll
                for (int j = 0; j < 4; ++j)
#pragma unroll
                    for (int b2 = 0; b2 < 4; ++b2)
                        if ((w[j] >> (8*b2)) & 0xffu) m |= 1u << (4*j + b2);
                b16[t] = (unsigned short)m;
            }
        } else {
            const long long n = NELEM / 4;
            const int l3 = tid & 3;
            for (long long t = T; t < n; t += nth) {
                const uint4 u = src[t];
                const unsigned int nib = (u.x ? 1u : 0u) | (u.y ? 2u : 0u) |
                                         (u.z ? 4u : 0u) | (u.w ? 8u : 0u);
                unsigned int vv = nib << (4*l3);
                vv |= __shfl_xor(vv, 1, 64);
                vv |= __shfl_xor(vv, 2, 64);
                if (l3 == 0) b16[t >> 2] = (unsigned short)vv;
            }
        }
    }
}

// ---------------------------------------------------------------------------
// Split-bf16 MFMA GEMM, MODE 2 only (final projection): 3-term, fp32 out.
// ---------------------------------------------------------------------------
template<int MODE>
__global__ __launch_bounds__(256) void gemm_split(
    const float* __restrict__ A,
    const unsigned short* __restrict__ WTh,
    const unsigned short* __restrict__ WTl,
    const float* __restrict__ bias,
    void* __restrict__ outv, const float oscale)
{
    __shared__ unsigned short Ah[64][64], Al[64][64], Bh[64][64], Bl[64][64];

    const int tid = threadIdx.x;
    const int w = tid >> 6, lane = tid & 63, g = lane >> 4, r = lane & 15;
    const int m0 = blockIdx.x * 64, n0 = blockIdx.y * 64;

    char* pAh = (char*)&Ah[0][0];
    char* pAl = (char*)&Al[0][0];
    char* pBh = (char*)&Bh[0][0];
    char* pBl = (char*)&Bl[0][0];

    const f32x4 z4 = {0.f, 0.f, 0.f, 0.f};
    f32x4 acc[4] = {z4, z4, z4, z4};

    for (int kt = 0; kt < DM_; kt += 64) {
#pragma unroll
        for (int rd = 0; rd < 4; ++rd) {
            const int row = (tid >> 4) + 16*rd;
            const int c4  = (tid & 15) * 4;
            const float4 a4 = *(const float4*)(A + (size_t)(m0 + row)*DM_ + kt + c4);
            const float av[4] = {a4.x, a4.y, a4.z, a4.w};
            unsigned short hh[4];
#pragma unroll
            for (int j = 0; j < 4; ++j) hh[j] = f2bf(av[j]);
            const int bo = (c4 * 2) ^ ((row & 7) << 4);
            *(ushort4*)(pAh + row*128 + bo) = make_ushort4(hh[0],hh[1],hh[2],hh[3]);
            if (MODE == 2) {
                unsigned short ll[4];
#pragma unroll
                for (int j = 0; j < 4; ++j) ll[j] = f2bf(av[j] - bf2f(hh[j]));
                *(ushort4*)(pAl + row*128 + bo) = make_ushort4(ll[0],ll[1],ll[2],ll[3]);
            }
        }
#pragma unroll
        for (int rd = 0; rd < 2; ++rd) {
            const int idx = tid + 256*rd;
            const int row = idx >> 3;
            const int cb  = (idx & 7) * 16;
            const int bo  = cb ^ ((row & 7) << 4);
            const size_t goff = (size_t)(n0 + row)*DM_ + kt + (cb >> 1);
            *(bf16x8*)(pBh + row*128 + bo) = *(const bf16x8*)(WTh + goff);
            *(bf16x8*)(pBl + row*128 + bo) = *(const bf16x8*)(WTl + goff);
        }
        __syncthreads();

        const int swr = (r & 7) << 4;
#pragma unroll
        for (int ks = 0; ks < 2; ++ks) {
            const int xo = (64*ks + 16*g) ^ swr;
            const bf16x8 xh = *(const bf16x8*)(pAh + (16*w + r)*128 + xo);
#pragma unroll
            for (int nt = 0; nt < 4; ++nt) {
                const bf16x8 bh = *(const bf16x8*)(pBh + (16*nt + r)*128 + xo);
                const bf16x8 bl = *(const bf16x8*)(pBl + (16*nt + r)*128 + xo);
                const bf16x8 xl = *(const bf16x8*)(pAl + (16*w + r)*128 + xo);
                acc[nt] = MFMA16(bh, xh, acc[nt]);
                acc[nt] = MFMA16(bh, xl, acc[nt]);
                acc[nt] = MFMA16(bl, xh, acc[nt]);
            }
        }
        __syncthreads();
    }

    {
        const int m = m0 + 16*w + r;
        float* dst = (float*)outv + (size_t)m*DM_ + n0;
#pragma unroll
        for (int nt = 0; nt < 4; ++nt) {
            float4 o4;
            o4.x = acc[nt][0] + bias[n0 + 16*nt + 4*g + 0];
            o4.y = acc[nt][1] + bias[n0 + 16*nt + 4*g + 1];
            o4.z = acc[nt][2] + bias[n0 + 16*nt + 4*g + 2];
            o4.w = acc[nt][3] + bias[n0 + 16*nt + 4*g + 3];
            *(float4*)(dst + 16*nt + 4*g) = o4;
        }
    }
    (void)oscale;
}

// ---------------------------------------------------------------------------
// MFMA flash attention: W DOUBLE-BUFFERED in LDS (2x16KB), K/V direct from
// L2 to registers (XCD-local after T1 remap), P bounce 8KB. 40KB LDS ->
// 4 blocks/CU AND stage(i+1) hidden under compute(i). K/V loads issue
// BEFORE stage(i+1), so compiler's counted K/V waits leave W-stage in
// flight; only vmcnt(0) is at the barrier (after a full compute phase).
// ---------------------------------------------------------------------------
__global__ __launch_bounds__(256, 4) void attn_mfma(
    const unsigned short* __restrict__ Qb,
    const unsigned short* __restrict__ Kb,
    const unsigned short* __restrict__ Vt,
    const float* __restrict__ Wt,
    const unsigned long long* __restrict__ Mb,
    float* __restrict__ O)
{
    __shared__ float WT[2][64][64];         // [buf][q][k] f32, cg16 ^= q&15
    __shared__ short Pl[4][1024];           // P bounce, wave-private 2KB

    const int tid  = threadIdx.x;
    const int wv   = tid >> 6, lane = tid & 63;
    const int g    = lane >> 4, r = lane & 15;

    // ---- XCD-aware decode (bijective on 1024) ----
    const int l    = blockIdx.x;
    const int xcd  = l & 7, t = l >> 3;
    const int bh   = ((t >> 5) << 3) + xcd;
    const int qblk = t & 31;
    const int q0   = qblk * 64 + wv * 16;

    const size_t kvBase = (size_t)bh * NK_ * DK_;
    const unsigned short* qp = Qb + kvBase + (size_t)(q0 + r)*DK_ + 8*g;
    const bf16x8 qf0 = *(const bf16x8*)qp;
    const bf16x8 qf1 = *(const bf16x8*)(qp + 32);

    const float* wblock = Wt + ((size_t)bh*NQ_ + qblk*64)*NK_;
    const unsigned long long* brow = Mb + ((size_t)bh*NQ_ + q0 + r)*(NK_/64);
    const unsigned short* kbase = Kb + kvBase + (size_t)r*DK_ + 8*g;
    const unsigned short* vbase = Vt + kvBase + (size_t)r*NK_ + 8*g;

    const f32x4 zero4 = {0.f, 0.f, 0.f, 0.f};
    f32x4 oa0 = zero4, oa1 = zero4, oa2 = zero4, oa3 = zero4;
    float m_run = -1e30f, l_run = 0.f;

    char* pbase = (char*)&Pl[wv][0];
    const int roff = r * 128;
    const int sw   = (r & 7) << 4;
    const int w_r4 = lane >> 4;

    // stage W 64x64 f32 tile for key offset kt into buffer pbuf
    auto stageW = [&](int pbuf, int kt) {
#pragma unroll
        for (int c = 0; c < 4; ++c) {
            const int rowl = 16*wv + c*4 + w_r4;
            glds16(wblock + (size_t)rowl*NK_ + kt + 4*((lane & 15) ^ (c*4 + w_r4)),
                   &WT[pbuf][16*wv + c*4][0] + lane*4);
        }
    };

#define LOADK(ktv) do { \
    const unsigned short* kp_ = kbase + (size_t)(ktv)*DK_;      \
    k00 = *(const bf16x8*)kp_;         k01 = *(const bf16x8*)(kp_ + 32);          \
    k10 = *(const bf16x8*)(kp_+1024);  k11 = *(const bf16x8*)(kp_ + 1024 + 32);   \
    k20 = *(const bf16x8*)(kp_+2048);  k21 = *(const bf16x8*)(kp_ + 2048 + 32);   \
    k30 = *(const bf16x8*)(kp_+3072);  k31 = *(const bf16x8*)(kp_ + 3072 + 32);   \
} while (0)

#define LOADV(ktv) do { \
    const unsigned short* vp_ = vbase + (ktv);                  \
    v00 = *(const bf16x8*)(vp_);             v01 = *(const bf16x8*)(vp_ + 16*NK_);      \
    v02 = *(const bf16x8*)(vp_ + 32*NK_);    v03 = *(const bf16x8*)(vp_ + 48*NK_);      \
    v10 = *(const bf16x8*)(vp_ + 32);        v11 = *(const bf16x8*)(vp_ + 16*NK_ + 32); \
    v12 = *(const bf16x8*)(vp_ + 32*NK_+32); v13 = *(const bf16x8*)(vp_ + 48*NK_ + 32); \
} while (0)

    bf16x8 k00,k01,k10,k11,k20,k21,k30,k31;
    bf16x8 v00,v01,v02,v03, v10,v11,v12,v13;

    // ---- prologue: stage W(0), drain ----
    stageW(0, 0);
    __syncthreads();

#pragma unroll 1
    for (int i = 0; i < 32; ++i) {
        const int p  = i & 1;
        const int kt = i * 64;

        // ---- K(i) register loads (L2/XCD-local), then stage W(i+1) ----
        LOADK(kt);
        if (i + 1 < 32) stageW(p ^ 1, kt + 64);
        const unsigned long long bcur = brow[i];

        // ---- QK MFMA (counted K-wait leaves W-stage in flight) ----
        f32x4 sa0 = zero4, sa1 = zero4, sa2 = zero4, sa3 = zero4;
        sa0 = MFMA16(k00, qf0, sa0); sa0 = MFMA16(k01, qf1, sa0);
        sa1 = MFMA16(k10, qf0, sa1); sa1 = MFMA16(k11, qf1, sa1);
        sa2 = MFMA16(k20, qf0, sa2); sa2 = MFMA16(k21, qf1, sa2);
        sa3 = MFMA16(k30, qf0, sa3); sa3 = MFMA16(k31, qf1, sa3);

        // ---- W fragments from current buffer ----
        f32x4 wf[4];
#pragma unroll
        for (int t2 = 0; t2 < 4; ++t2)
            wf[t2] = *(const f32x4*)&WT[p][16*wv + r][4*((4*t2 + g) ^ r)];

        // ---- logits + mask ----
        float lg[16];
        const f32x4 sav[4] = {sa0, sa1, sa2, sa3};
#pragma unroll
        for (int t2 = 0; t2 < 4; ++t2) {
            const unsigned int half = (t2 & 2) ? (unsigned int)(bcur >> 32)
                                               : (unsigned int)bcur;
#pragma unroll
            for (int j = 0; j < 4; ++j) {
                const unsigned int bit = (half >> (16*(t2 & 1) + 4*g + j)) & 1u;
                lg[4*t2+j] = bit ? -1e30f : sav[t2][j] * wf[t2][j];
            }
        }

        // ---- online softmax ----
        float mx = lg[0];
#pragma unroll
        for (int i2 = 1; i2 < 16; ++i2) mx = fmaxf(mx, lg[i2]);
        mx = fmaxf(mx, __shfl_xor(mx, 16, 64));
        mx = fmaxf(mx, __shfl_xor(mx, 32, 64));
        const float mnew = fmaxf(m_run, mx);
        const float fsc  = __expf(m_run - mnew);
        m_run = mnew;
        float p16[16], rs = 0.f;
#pragma unroll
        for (int i2 = 0; i2 < 16; ++i2) { p16[i2] = __expf(lg[i2] - mnew); rs += p16[i2]; }
        rs += __shfl_xor(rs, 16, 64);
        rs += __shfl_xor(rs, 32, 64);
        l_run = l_run * fsc + rs;

        // ---- P pack -> wave-private LDS -> A-fragments ----
#pragma unroll
        for (int t2 = 0; t2 < 4; ++t2) {
            const unsigned int w0 = (unsigned int)f2bf(p16[4*t2+0]) |
                                    ((unsigned int)f2bf(p16[4*t2+1]) << 16);
            const unsigned int w1 = (unsigned int)f2bf(p16[4*t2+2]) |
                                    ((unsigned int)f2bf(p16[4*t2+3]) << 16);
            *(int2*)(pbase + roff + ((32*t2 + 8*g) ^ sw)) = make_int2((int)w0, (int)w1);
        }
        const bf16x8 pa0 = *(const bf16x8*)(pbase + roff + ((     16*g) ^ sw));
        const bf16x8 pa1 = *(const bf16x8*)(pbase + roff + ((64 + 16*g) ^ sw));

        // ---- V(i) register loads (short live range, after P ready) ----
        LOADV(kt);

        // ---- rescale O ----
        float fr[4];
#pragma unroll
        for (int j = 0; j < 4; ++j) fr[j] = __shfl(fsc, 4*g + j, 64);
#pragma unroll
        for (int j = 0; j < 4; ++j) {
            oa0[j] *= fr[j]; oa1[j] *= fr[j]; oa2[j] *= fr[j]; oa3[j] *= fr[j];
        }

        // ---- PV ----
        oa0 = MFMA16(pa0, v00, oa0); oa1 = MFMA16(pa0, v01, oa1);
        oa2 = MFMA16(pa0, v02, oa2); oa3 = MFMA16(pa0, v03, oa3);
        oa0 = MFMA16(pa1, v10, oa0); oa1 = MFMA16(pa1, v11, oa1);
        oa2 = MFMA16(pa1, v12, oa2); oa3 = MFMA16(pa1, v13, oa3);

        // one barrier per iter: drains stage(i+1) (covered by compute),
        // protects WT[p] reuse and wave-private P
        __syncthreads();
    }
#undef LOADK
#undef LOADV

    // ---- epilogue: normalize + write (b, q, h*64+dv) fp32 ----
    const float inv = 1.0f / l_run;
    float ir[4];
#pragma unroll
    for (int j = 0; j < 4; ++j) ir[j] = __shfl(inv, 4*g + j, 64);
    const int bb = bh >> 3, h = bh & 7;
    const f32x4 oav[4] = {oa0, oa1, oa2, oa3};
#pragma unroll
    for (int nt = 0; nt < 4; ++nt)
#pragma unroll
        for (int j = 0; j < 4; ++j)
            O[((size_t)(bb*NQ_ + q0 + 4*g + j))*DM_ + h*64 + 16*nt + r] = oav[nt][j] * ir[j];
}

// ---------------------------------------------------------------------------
extern "C" void kernel_launch(void* const* d_in, const int* in_sizes, int n_in,
                              void* d_out, int out_size, void* d_ws, size_t ws_size,
                              hipStream_t stream) {
    (void)in_sizes; (void)n_in; (void)out_size; (void)ws_size;

    const float* q    = (const float*)d_in[0];
    const float* k    = (const float*)d_in[1];
    const float* v    = (const float*)d_in[2];
    const float* attw = (const float*)d_in[3];
    const unsigned char* mask = (const unsigned char*)d_in[4];
    const float* Wq = (const float*)d_in[5];
    const float* bq = (const float*)d_in[6];
    const float* Wk = (const float*)d_in[7];
    const float* bk = (const float*)d_in[8];
    const float* Wv = (const float*)d_in[9];
    const float* bv = (const float*)d_in[10];
    const float* Wo = (const float*)d_in[11];
    const float* bo = (const float*)d_in[12];
    float* out = (float*)d_out;

    // ws (shorts): q_bf[NE] k_bf[NE] vT[NE] wt[8*WL] | bits[2Mi u64] | o_ws fp32
    const long long NE = (long long)B_*H_*NQ_*DK_;        // 4Mi
    unsigned short* q_bf = (unsigned short*)d_ws;
    unsigned short* k_bf = q_bf + NE;
    unsigned short* vT   = q_bf + 2*NE;
    unsigned short* wt   = q_bf + 3*NE;
    unsigned long long* bits = (unsigned long long*)(wt + 8LL*WL_);
    const long long NB = (long long)B_*H_*NQ_*NK_/64;     // 2Mi
    float* o_ws = (float*)(bits + NB);

    const dim3 blk(256);
    wprep<<<dim3(8, 8, 4), blk, 0, stream>>>(Wq, Wk, Wv, Wo, wt);

    // fused: 3 projections (z=0..2) + mask conversion (z=3..4)
    proj_mask<<<dim3(128, 8, 5), blk, 0, stream>>>(q, k, v, wt, bq, bk, bv,
                                                   q_bf, k_bf, vT, mask, bits);

    attn_mfma<<<dim3(1024), blk, 0, stream>>>(q_bf, k_bf, vT, attw, bits, o_ws);

    gemm_split<2><<<dim3(128, 8), blk, 0, stream>>>(o_ws, wt + 6*WL_, wt + 7*WL_, bo, out, 1.0f);
}

// Round 19
// 340.641 us; speedup vs baseline: 1.4183x; 1.4183x over previous
//
#include <hip/hip_runtime.h>
#include <hip/hip_bf16.h>
#include <math.h>

#define B_   4
#define H_   8
#define NQ_  2048
#define NK_  2048
#define DM_  512
#define DK_  64
#define WL_  262144   // 512*512

typedef short  bf16x8 __attribute__((ext_vector_type(8)));
typedef float  f32x4  __attribute__((ext_vector_type(4)));

static __device__ __forceinline__ f32x4 MFMA16(bf16x8 a, bf16x8 b, f32x4 c) {
    return __builtin_amdgcn_mfma_f32_16x16x32_bf16(a, b, c, 0, 0, 0);
}
static __device__ __forceinline__ unsigned short f2bf(float f) {
    __hip_bfloat16 h = __float2bfloat16(f);
    unsigned short u; __builtin_memcpy(&u, &h, 2); return u;
}
static __device__ __forceinline__ float bf2f(unsigned short u) {
    unsigned int x = ((unsigned int)u) << 16;
    float f; __builtin_memcpy(&f, &x, 4); return f;
}
static __device__ __forceinline__ void glds16(const void* g, void* l) {
    __builtin_amdgcn_global_load_lds(
        (__attribute__((address_space(1))) const void*)g,
        (__attribute__((address_space(3))) void*)l, 16, 0, 0);
}

// ---------------------------------------------------------------------------
// W (512x512 fp32, [k][n]) -> WT_hi/WT_lo (bf16, [n][k]) for all 4 weights
// ---------------------------------------------------------------------------
__global__ __launch_bounds__(256) void wprep(const float* __restrict__ Wq,
                                             const float* __restrict__ Wk,
                                             const float* __restrict__ Wv,
                                             const float* __restrict__ Wo,
                                             unsigned short* __restrict__ out)
{
    __shared__ float tile[64][65];
    const int tid = threadIdx.x;
    const int k0 = blockIdx.x * 64, n0 = blockIdx.y * 64, w = blockIdx.z;
    const float* W = (w == 0) ? Wq : (w == 1) ? Wk : (w == 2) ? Wv : Wo;
    unsigned short* WTh = out + (size_t)w * 2 * WL_;
    unsigned short* WTl = WTh + WL_;

#pragma unroll
    for (int rd = 0; rd < 4; ++rd) {
        const int k = (tid >> 4) + 16*rd, c4 = (tid & 15) * 4;
        const float4 v4 = *(const float4*)(W + (size_t)(k0 + k)*DM_ + n0 + c4);
        tile[k][c4+0] = v4.x; tile[k][c4+1] = v4.y;
        tile[k][c4+2] = v4.z; tile[k][c4+3] = v4.w;
    }
    __syncthreads();
#pragma unroll
    for (int rd = 0; rd < 4; ++rd) {
        const int n = (tid >> 4) + 16*rd, kk = (tid & 15) * 4;
        unsigned short hh[4], ll[4];
#pragma unroll
        for (int j = 0; j < 4; ++j) {
            const float f = tile[kk + j][n];
            hh[j] = f2bf(f);
            ll[j] = f2bf(f - bf2f(hh[j]));
        }
        *(ushort4*)(WTh + (size_t)(n0 + n)*DM_ + k0 + kk) = make_ushort4(hh[0],hh[1],hh[2],hh[3]);
        *(ushort4*)(WTl + (size_t)(n0 + n)*DM_ + k0 + kk) = make_ushort4(ll[0],ll[1],ll[2],ll[3]);
    }
}

// ---------------------------------------------------------------------------
// FUSED: 3 projection GEMMs (z=0,1,2) + mask->bits conversion (z=3,4).
// ---------------------------------------------------------------------------
__global__ __launch_bounds__(256) void proj_mask(
    const float* __restrict__ q, const float* __restrict__ k,
    const float* __restrict__ v,
    const unsigned short* __restrict__ wt,
    const float* __restrict__ bq, const float* __restrict__ bk,
    const float* __restrict__ bv,
    unsigned short* __restrict__ q_bf, unsigned short* __restrict__ k_bf,
    unsigned short* __restrict__ vT,
    const unsigned char* __restrict__ Mk,
    unsigned long long* __restrict__ bits)
{
    __shared__ unsigned short Ah[64][64], Bh[64][64], Bl[64][64];
    __shared__ int s_flag;

    const int tid = threadIdx.x;
    const int z = blockIdx.z;

    if (z < 3) {
        const float* A = (z == 0) ? q : (z == 1) ? k : v;
        const unsigned short* WTh = wt + (size_t)(2*z) * WL_;
        const unsigned short* WTl = WTh + WL_;
        const float* bias = (z == 0) ? bq : (z == 1) ? bk : bv;
        const float oscale = (z == 0) ? 0.125f : 1.0f;
        const int mode = (z == 2) ? 1 : 0;

        const int w = tid >> 6, lane = tid & 63, g = lane >> 4, r = lane & 15;
        const int m0 = blockIdx.x * 64, n0 = blockIdx.y * 64;

        char* pAh = (char*)&Ah[0][0];
        char* pBh = (char*)&Bh[0][0];
        char* pBl = (char*)&Bl[0][0];

        const f32x4 z4 = {0.f, 0.f, 0.f, 0.f};
        f32x4 acc[4] = {z4, z4, z4, z4};

        for (int kt = 0; kt < DM_; kt += 64) {
#pragma unroll
            for (int rd = 0; rd < 4; ++rd) {
                const int row = (tid >> 4) + 16*rd;
                const int c4  = (tid & 15) * 4;
                const float4 a4 = *(const float4*)(A + (size_t)(m0 + row)*DM_ + kt + c4);
                const float av[4] = {a4.x, a4.y, a4.z, a4.w};
                unsigned short hh[4];
#pragma unroll
                for (int j = 0; j < 4; ++j) hh[j] = f2bf(av[j]);
                const int bo = (c4 * 2) ^ ((row & 7) << 4);
                *(ushort4*)(pAh + row*128 + bo) = make_ushort4(hh[0],hh[1],hh[2],hh[3]);
            }
#pragma unroll
            for (int rd = 0; rd < 2; ++rd) {
                const int idx = tid + 256*rd;
                const int row = idx >> 3;
                const int cb  = (idx & 7) * 16;
                const int bo  = cb ^ ((row & 7) << 4);
                const size_t goff = (size_t)(n0 + row)*DM_ + kt + (cb >> 1);
                *(bf16x8*)(pBh + row*128 + bo) = *(const bf16x8*)(WTh + goff);
                *(bf16x8*)(pBl + row*128 + bo) = *(const bf16x8*)(WTl + goff);
            }
            __syncthreads();

            const int swr = (r & 7) << 4;
#pragma unroll
            for (int ks = 0; ks < 2; ++ks) {
                const int xo = (64*ks + 16*g) ^ swr;
                const bf16x8 xh = *(const bf16x8*)(pAh + (16*w + r)*128 + xo);
#pragma unroll
                for (int nt = 0; nt < 4; ++nt) {
                    const bf16x8 bh = *(const bf16x8*)(pBh + (16*nt + r)*128 + xo);
                    const bf16x8 bl = *(const bf16x8*)(pBl + (16*nt + r)*128 + xo);
                    if (mode == 1) {
                        acc[nt] = MFMA16(xh, bh, acc[nt]);
                        acc[nt] = MFMA16(xh, bl, acc[nt]);
                    } else {
                        acc[nt] = MFMA16(bh, xh, acc[nt]);
                        acc[nt] = MFMA16(bl, xh, acc[nt]);
                    }
                }
            }
            __syncthreads();
        }

        if (mode == 0) {
            const int m = m0 + 16*w + r;
            const int b = m >> 11, qq = m & 2047, h = blockIdx.y;
            unsigned short* dstp = (z == 0 ? q_bf : k_bf) +
                                   (((size_t)(b*H_ + h))*NQ_ + qq)*DK_;
#pragma unroll
            for (int nt = 0; nt < 4; ++nt) {
                unsigned short u[4];
#pragma unroll
                for (int j = 0; j < 4; ++j)
                    u[j] = f2bf((acc[nt][j] + bias[n0 + 16*nt + 4*g + j]) * oscale);
                *(ushort4*)(dstp + 16*nt + 4*g) = make_ushort4(u[0],u[1],u[2],u[3]);
            }
        } else {
            const int b = m0 >> 11, h = blockIdx.y;
            const int key = (m0 & 2047) + 16*w + 4*g;
#pragma unroll
            for (int nt = 0; nt < 4; ++nt) {
                const int dv = 16*nt + r;
                const float bvv = bias[n0 + dv];
                unsigned short u[4];
#pragma unroll
                for (int j = 0; j < 4; ++j) u[j] = f2bf(acc[nt][j] + bvv);
                *(ushort4*)(vT + (((size_t)(b*H_ + h))*DK_ + dv)*NK_ + key) =
                    make_ushort4(u[0],u[1],u[2],u[3]);
            }
        }
    } else {
        // ---------------- mask -> bits (grid-stride) ----------------
        if (tid == 0) s_flag = 0;
        __syncthreads();
        {
            bool any = false;
#pragma unroll
            for (int i = 1; i < 16; i += 4)
                if (Mk[tid*16 + i]) any = true;
            if (any) s_flag = 1;
        }
        __syncthreads();

        const long long NELEM = (long long)B_*H_*NQ_*NK_;      // 128Mi
        const long long nblk  = 2LL * gridDim.x * gridDim.y;   // 2048
        const long long nth   = nblk * 256;
        const long long id    = ((long long)(z - 3) * gridDim.x * gridDim.y +
                                 (long long)blockIdx.y * gridDim.x + blockIdx.x);
        const long long T     = id * 256 + tid;
        unsigned short* b16   = (unsigned short*)bits;
        const uint4*    src   = (const uint4*)Mk;

        if (s_flag) {
            const long long n = NELEM / 16;
            for (long long t = T; t < n; t += nth) {
                const uint4 u = src[t];
                const unsigned int w[4] = {u.x, u.y, u.z, u.w};
                unsigned int m = 0;
#pragma unroll
                for (int j = 0; j < 4; ++j)
#pragma unroll
                    for (int b2 = 0; b2 < 4; ++b2)
                        if ((w[j] >> (8*b2)) & 0xffu) m |= 1u << (4*j + b2);
                b16[t] = (unsigned short)m;
            }
        } else {
            const long long n = NELEM / 4;
            const int l3 = tid & 3;
            for (long long t = T; t < n; t += nth) {
                const uint4 u = src[t];
                const unsigned int nib = (u.x ? 1u : 0u) | (u.y ? 2u : 0u) |
                                         (u.z ? 4u : 0u) | (u.w ? 8u : 0u);
                unsigned int vv = nib << (4*l3);
                vv |= __shfl_xor(vv, 1, 64);
                vv |= __shfl_xor(vv, 2, 64);
                if (l3 == 0) b16[t >> 2] = (unsigned short)vv;
            }
        }
    }
}

// ---------------------------------------------------------------------------
// Split-bf16 MFMA GEMM, MODE 2 only (final projection): 3-term, fp32 out.
// ---------------------------------------------------------------------------
template<int MODE>
__global__ __launch_bounds__(256) void gemm_split(
    const float* __restrict__ A,
    const unsigned short* __restrict__ WTh,
    const unsigned short* __restrict__ WTl,
    const float* __restrict__ bias,
    void* __restrict__ outv, const float oscale)
{
    __shared__ unsigned short Ah[64][64], Al[64][64], Bh[64][64], Bl[64][64];

    const int tid = threadIdx.x;
    const int w = tid >> 6, lane = tid & 63, g = lane >> 4, r = lane & 15;
    const int m0 = blockIdx.x * 64, n0 = blockIdx.y * 64;

    char* pAh = (char*)&Ah[0][0];
    char* pAl = (char*)&Al[0][0];
    char* pBh = (char*)&Bh[0][0];
    char* pBl = (char*)&Bl[0][0];

    const f32x4 z4 = {0.f, 0.f, 0.f, 0.f};
    f32x4 acc[4] = {z4, z4, z4, z4};

    for (int kt = 0; kt < DM_; kt += 64) {
#pragma unroll
        for (int rd = 0; rd < 4; ++rd) {
            const int row = (tid >> 4) + 16*rd;
            const int c4  = (tid & 15) * 4;
            const float4 a4 = *(const float4*)(A + (size_t)(m0 + row)*DM_ + kt + c4);
            const float av[4] = {a4.x, a4.y, a4.z, a4.w};
            unsigned short hh[4];
#pragma unroll
            for (int j = 0; j < 4; ++j) hh[j] = f2bf(av[j]);
            const int bo = (c4 * 2) ^ ((row & 7) << 4);
            *(ushort4*)(pAh + row*128 + bo) = make_ushort4(hh[0],hh[1],hh[2],hh[3]);
            if (MODE == 2) {
                unsigned short ll[4];
#pragma unroll
                for (int j = 0; j < 4; ++j) ll[j] = f2bf(av[j] - bf2f(hh[j]));
                *(ushort4*)(pAl + row*128 + bo) = make_ushort4(ll[0],ll[1],ll[2],ll[3]);
            }
        }
#pragma unroll
        for (int rd = 0; rd < 2; ++rd) {
            const int idx = tid + 256*rd;
            const int row = idx >> 3;
            const int cb  = (idx & 7) * 16;
            const int bo  = cb ^ ((row & 7) << 4);
            const size_t goff = (size_t)(n0 + row)*DM_ + kt + (cb >> 1);
            *(bf16x8*)(pBh + row*128 + bo) = *(const bf16x8*)(WTh + goff);
            *(bf16x8*)(pBl + row*128 + bo) = *(const bf16x8*)(WTl + goff);
        }
        __syncthreads();

        const int swr = (r & 7) << 4;
#pragma unroll
        for (int ks = 0; ks < 2; ++ks) {
            const int xo = (64*ks + 16*g) ^ swr;
            const bf16x8 xh = *(const bf16x8*)(pAh + (16*w + r)*128 + xo);
#pragma unroll
            for (int nt = 0; nt < 4; ++nt) {
                const bf16x8 bh = *(const bf16x8*)(pBh + (16*nt + r)*128 + xo);
                const bf16x8 bl = *(const bf16x8*)(pBl + (16*nt + r)*128 + xo);
                const bf16x8 xl = *(const bf16x8*)(pAl + (16*w + r)*128 + xo);
                acc[nt] = MFMA16(bh, xh, acc[nt]);
                acc[nt] = MFMA16(bh, xl, acc[nt]);
                acc[nt] = MFMA16(bl, xh, acc[nt]);
            }
        }
        __syncthreads();
    }

    {
        const int m = m0 + 16*w + r;
        float* dst = (float*)outv + (size_t)m*DM_ + n0;
#pragma unroll
        for (int nt = 0; nt < 4; ++nt) {
            float4 o4;
            o4.x = acc[nt][0] + bias[n0 + 16*nt + 4*g + 0];
            o4.y = acc[nt][1] + bias[n0 + 16*nt + 4*g + 1];
            o4.z = acc[nt][2] + bias[n0 + 16*nt + 4*g + 2];
            o4.w = acc[nt][3] + bias[n0 + 16*nt + 4*g + 3];
            *(float4*)(dst + 16*nt + 4*g) = o4;
        }
    }
    (void)oscale;
}

// ---------------------------------------------------------------------------
// MFMA flash attention, r13 structure + T1 XCD-aware block remap (r17 best):
// 1D grid 1024; linear id l built so all 32 q-blocks of one (b,h) land on
// the SAME XCD (l%8 == bh%8): K/V re-reads become per-XCD L2 hits.
// decode: x=l&7, t=l>>3, bh=(t>>5)*8+x, qblk=t&31.
// ---------------------------------------------------------------------------
__global__ __launch_bounds__(256, 4) void attn_mfma(
    const unsigned short* __restrict__ Qb,
    const unsigned short* __restrict__ Kb,
    const unsigned short* __restrict__ Vt,
    const float* __restrict__ Wt,
    const unsigned long long* __restrict__ Mb,
    float* __restrict__ O)
{
    __shared__ unsigned short KT[64][64];   // [key][dim] bf16, cg16 ^= key&7
    __shared__ unsigned short VTs[64][64];  // [dv][key]  bf16, cg16 ^= dv&7
    __shared__ float          WT[64][64];   // [q][k]     f32,  cg16 ^= q&15
    __shared__ short          Pl[4][1024];  // P bounce, wave-private 2KB

    const int tid  = threadIdx.x;
    const int wv   = tid >> 6, lane = tid & 63;
    const int g    = lane >> 4, r = lane & 15;

    // ---- XCD-aware decode (bijective on 1024) ----
    const int l    = blockIdx.x;
    const int xcd  = l & 7, t = l >> 3;
    const int bh   = ((t >> 5) << 3) + xcd;   // all 32 q-blocks of bh share l%8
    const int qblk = t & 31;
    const int q0   = qblk * 64 + wv * 16;

    const size_t kvBase = (size_t)bh * NK_ * DK_;
    const unsigned short* qp = Qb + kvBase + (size_t)(q0 + r)*DK_ + 8*g;
    const bf16x8 qf0 = *(const bf16x8*)qp;
    const bf16x8 qf1 = *(const bf16x8*)(qp + 32);

    const float* wblock = Wt + ((size_t)bh*NQ_ + qblk*64)*NK_;
    const unsigned long long* brow = Mb + ((size_t)bh*NQ_ + q0 + r)*(NK_/64);
    const unsigned short* kg = Kb + kvBase;            // [key][64]
    const unsigned short* vg = Vt + kvBase;            // [dv][NK]

    const f32x4 zero4 = {0.f, 0.f, 0.f, 0.f};
    f32x4 oa0 = zero4, oa1 = zero4, oa2 = zero4, oa3 = zero4;
    float m_run = -1e30f, l_run = 0.f;

    char* pbase = (char*)&Pl[wv][0];
    const int roff = r * 128;
    const int sw   = (r & 7) << 4;

    // per-lane staging constants
    const int kv_soff = 8 * ((lane & 7) ^ (lane >> 3));   // shorts, swizzled src col
    const int kv_r8   = lane >> 3;                        // row within 8-row chunk
    const int w_r4    = lane >> 4;                        // row within 4-row chunk

#pragma unroll 1
    for (int i = 0; i < 32; ++i) {
        const int kt = i * 64;

        // ---- stage phase: K, V, W via glds (pre-swizzled sources) ----
#pragma unroll
        for (int c = 0; c < 2; ++c) {
            const int rowl = 16*wv + c*8 + kv_r8;         // key / dv row in tile
            glds16(kg + (size_t)(kt + rowl)*DK_ + kv_soff,
                   &KT[16*wv + c*8][0] + lane*8);
            glds16(vg + (size_t)rowl*NK_ + kt + kv_soff,
                   &VTs[16*wv + c*8][0] + lane*8);
        }
#pragma unroll
        for (int c = 0; c < 4; ++c) {
            const int rowl = 16*wv + c*4 + w_r4;          // q row in tile
            glds16(wblock + (size_t)rowl*NK_ + kt + 4*((lane & 15) ^ (c*4 + w_r4)),
                   &WT[16*wv + c*4][0] + lane*4);
        }
        const unsigned long long bcur = brow[i];
        __syncthreads();

        // ---- compute phase (plain C; compiler manages waits) ----
        f32x4 sa0 = zero4, sa1 = zero4, sa2 = zero4, sa3 = zero4;
        {
            const bf16x8 k00 = *(const bf16x8*)&KT[ 0 + r][8*((g    ) ^ (r & 7))];
            const bf16x8 k01 = *(const bf16x8*)&KT[ 0 + r][8*((g + 4) ^ (r & 7))];
            const bf16x8 k10 = *(const bf16x8*)&KT[16 + r][8*((g    ) ^ (r & 7))];
            const bf16x8 k11 = *(const bf16x8*)&KT[16 + r][8*((g + 4) ^ (r & 7))];
            const bf16x8 k20 = *(const bf16x8*)&KT[32 + r][8*((g    ) ^ (r & 7))];
            const bf16x8 k21 = *(const bf16x8*)&KT[32 + r][8*((g + 4) ^ (r & 7))];
            const bf16x8 k30 = *(const bf16x8*)&KT[48 + r][8*((g    ) ^ (r & 7))];
            const bf16x8 k31 = *(const bf16x8*)&KT[48 + r][8*((g + 4) ^ (r & 7))];
            sa0 = MFMA16(k00, qf0, sa0); sa0 = MFMA16(k01, qf1, sa0);
            sa1 = MFMA16(k10, qf0, sa1); sa1 = MFMA16(k11, qf1, sa1);
            sa2 = MFMA16(k20, qf0, sa2); sa2 = MFMA16(k21, qf1, sa2);
            sa3 = MFMA16(k30, qf0, sa3); sa3 = MFMA16(k31, qf1, sa3);
        }

        f32x4 wf[4];
#pragma unroll
        for (int t2 = 0; t2 < 4; ++t2)
            wf[t2] = *(const f32x4*)&WT[16*wv + r][4*((4*t2 + g) ^ r)];

        float lg[16];
        const f32x4 sav[4] = {sa0, sa1, sa2, sa3};
#pragma unroll
        for (int t2 = 0; t2 < 4; ++t2) {
            const unsigned int half = (t2 & 2) ? (unsigned int)(bcur >> 32)
                                               : (unsigned int)bcur;
#pragma unroll
            for (int j = 0; j < 4; ++j) {
                const unsigned int bit = (half >> (16*(t2 & 1) + 4*g + j)) & 1u;
                lg[4*t2+j] = bit ? -1e30f : sav[t2][j] * wf[t2][j];
            }
        }

        float mx = lg[0];
#pragma unroll
        for (int i2 = 1; i2 < 16; ++i2) mx = fmaxf(mx, lg[i2]);
        mx = fmaxf(mx, __shfl_xor(mx, 16, 64));
        mx = fmaxf(mx, __shfl_xor(mx, 32, 64));
        const float mnew = fmaxf(m_run, mx);
        const float fsc  = __expf(m_run - mnew);
        m_run = mnew;
        float p16[16], rs = 0.f;
#pragma unroll
        for (int i2 = 0; i2 < 16; ++i2) { p16[i2] = __expf(lg[i2] - mnew); rs += p16[i2]; }
        rs += __shfl_xor(rs, 16, 64);
        rs += __shfl_xor(rs, 32, 64);
        l_run = l_run * fsc + rs;

#pragma unroll
        for (int t2 = 0; t2 < 4; ++t2) {
            const unsigned int w0 = (unsigned int)f2bf(p16[4*t2+0]) |
                                    ((unsigned int)f2bf(p16[4*t2+1]) << 16);
            const unsigned int w1 = (unsigned int)f2bf(p16[4*t2+2]) |
                                    ((unsigned int)f2bf(p16[4*t2+3]) << 16);
            *(int2*)(pbase + roff + ((32*t2 + 8*g) ^ sw)) = make_int2((int)w0, (int)w1);
        }
        const bf16x8 pa0 = *(const bf16x8*)(pbase + roff + ((     16*g) ^ sw));
        const bf16x8 pa1 = *(const bf16x8*)(pbase + roff + ((64 + 16*g) ^ sw));

        float fr[4];
#pragma unroll
        for (int j = 0; j < 4; ++j) fr[j] = __shfl(fsc, 4*g + j, 64);
#pragma unroll
        for (int j = 0; j < 4; ++j) {
            oa0[j] *= fr[j]; oa1[j] *= fr[j]; oa2[j] *= fr[j]; oa3[j] *= fr[j];
        }

        {
            const bf16x8 v00 = *(const bf16x8*)&VTs[ 0 + r][8*((g    ) ^ (r & 7))];
            const bf16x8 v01 = *(const bf16x8*)&VTs[16 + r][8*((g    ) ^ (r & 7))];
            const bf16x8 v02 = *(const bf16x8*)&VTs[32 + r][8*((g    ) ^ (r & 7))];
            const bf16x8 v03 = *(const bf16x8*)&VTs[48 + r][8*((g    ) ^ (r & 7))];
            const bf16x8 v10 = *(const bf16x8*)&VTs[ 0 + r][8*((g + 4) ^ (r & 7))];
            const bf16x8 v11 = *(const bf16x8*)&VTs[16 + r][8*((g + 4) ^ (r & 7))];
            const bf16x8 v12 = *(const bf16x8*)&VTs[32 + r][8*((g + 4) ^ (r & 7))];
            const bf16x8 v13 = *(const bf16x8*)&VTs[48 + r][8*((g + 4) ^ (r & 7))];
            oa0 = MFMA16(pa0, v00, oa0); oa1 = MFMA16(pa0, v01, oa1);
            oa2 = MFMA16(pa0, v02, oa2); oa3 = MFMA16(pa0, v03, oa3);
            oa0 = MFMA16(pa1, v10, oa0); oa1 = MFMA16(pa1, v11, oa1);
            oa2 = MFMA16(pa1, v12, oa2); oa3 = MFMA16(pa1, v13, oa3);
        }
        __syncthreads();
    }

    // ---- epilogue: normalize + write (b, q, h*64+dv) fp32 ----
    const float inv = 1.0f / l_run;
    float ir[4];
#pragma unroll
    for (int j = 0; j < 4; ++j) ir[j] = __shfl(inv, 4*g + j, 64);
    const int bb = bh >> 3, h = bh & 7;
    const f32x4 oav[4] = {oa0, oa1, oa2, oa3};
#pragma unroll
    for (int nt = 0; nt < 4; ++nt)
#pragma unroll
        for (int j = 0; j < 4; ++j)
            O[((size_t)(bb*NQ_ + q0 + 4*g + j))*DM_ + h*64 + 16*nt + r] = oav[nt][j] * ir[j];
}

// ---------------------------------------------------------------------------
extern "C" void kernel_launch(void* const* d_in, const int* in_sizes, int n_in,
                              void* d_out, int out_size, void* d_ws, size_t ws_size,
                              hipStream_t stream) {
    (void)in_sizes; (void)n_in; (void)out_size; (void)ws_size;

    const float* q    = (const float*)d_in[0];
    const float* k    = (const float*)d_in[1];
    const float* v    = (const float*)d_in[2];
    const float* attw = (const float*)d_in[3];
    const unsigned char* mask = (const unsigned char*)d_in[4];
    const float* Wq = (const float*)d_in[5];
    const float* bq = (const float*)d_in[6];
    const float* Wk = (const float*)d_in[7];
    const float* bk = (const float*)d_in[8];
    const float* Wv = (const float*)d_in[9];
    const float* bv = (const float*)d_in[10];
    const float* Wo = (const float*)d_in[11];
    const float* bo = (const float*)d_in[12];
    float* out = (float*)d_out;

    // ws (shorts): q_bf[NE] k_bf[NE] vT[NE] wt[8*WL] | bits[2Mi u64] | o_ws fp32
    const long long NE = (long long)B_*H_*NQ_*DK_;        // 4Mi
    unsigned short* q_bf = (unsigned short*)d_ws;
    unsigned short* k_bf = q_bf + NE;
    unsigned short* vT   = q_bf + 2*NE;
    unsigned short* wt   = q_bf + 3*NE;
    unsigned long long* bits = (unsigned long long*)(wt + 8LL*WL_);
    const long long NB = (long long)B_*H_*NQ_*NK_/64;     // 2Mi
    float* o_ws = (float*)(bits + NB);

    const dim3 blk(256);
    wprep<<<dim3(8, 8, 4), blk, 0, stream>>>(Wq, Wk, Wv, Wo, wt);

    // fused: 3 projections (z=0..2) + mask conversion (z=3..4)
    proj_mask<<<dim3(128, 8, 5), blk, 0, stream>>>(q, k, v, wt, bq, bk, bv,
                                                   q_bf, k_bf, vT, mask, bits);

    attn_mfma<<<dim3(1024), blk, 0, stream>>>(q_bf, k_bf, vT, attw, bits, o_ws);

    gemm_split<2><<<dim3(128, 8), blk, 0, stream>>>(o_ws, wt + 6*WL_, wt + 7*WL_, bo, out, 1.0f);
}